// Round 3
// baseline (115.273 us; speedup 1.0000x reference)
//
#include <hip/hip_runtime.h>
#include <hip/hip_bf16.h>

// ---- problem constants ----
#define HID   1024
#define NEXP  8
#define NPAIR 4096                       // TOKENS * TOPK
#define BMPAD 128                        // segment padding = BM
#define PERM_MAX (NPAIR + NEXP * BMPAD)  // 5120
#define MT_MAX (PERM_MAX / 128)          // 40 M-tiles

typedef unsigned short u16;
typedef __attribute__((ext_vector_type(8))) short bf16x8;
typedef __attribute__((ext_vector_type(4))) float f32x4;
typedef __attribute__((ext_vector_type(4))) unsigned short us4;
typedef __attribute__((ext_vector_type(4))) unsigned int u32x4;

static __device__ __forceinline__ u16 f2bf(float f) {
  union { float f; unsigned u; } v; v.f = f;
  unsigned u = v.u;
  unsigned r = (u + 0x7fffu + ((u >> 16) & 1u)) >> 16;
  return (u16)r;
}

// pack 2 f32 -> 2 bf16 in one u32 (expect v_cvt_pk_bf16_f32)
static __device__ __forceinline__ unsigned pk2(float a, float b) {
  __hip_bfloat162 h = __float22bfloat162_rn(make_float2(a, b));
  union { __hip_bfloat162 h; unsigned u; } c; c.h = h; return c.u;
}

static __device__ __forceinline__ void gload16(const void* g, void* l) {
  __builtin_amdgcn_global_load_lds(
      (const __attribute__((address_space(1))) unsigned int*)g,
      (__attribute__((address_space(3))) unsigned int*)l, 16, 0, 0);
}

static __device__ __forceinline__ f32x4 mfma_bf16(bf16x8 a, bf16x8 b, f32x4 c) {
  return __builtin_amdgcn_mfma_f32_16x16x32_bf16(a, b, c, 0, 0, 0);
}

// ---- prep: zero d_out, convert x -> bf16 ----
__global__ __launch_bounds__(256) void k_prep(const float* __restrict__ x,
                                              u16* __restrict__ xb,
                                              float* __restrict__ out) {
  int i = blockIdx.x * 256 + threadIdx.x;   // 1024 blocks * 256 thr * 8 elems = 2M
  int base = i * 8;
  f32x4 v0 = *(const f32x4*)(x + base);
  f32x4 v1 = *(const f32x4*)(x + base + 4);
  us4 a = { f2bf(v0[0]), f2bf(v0[1]), f2bf(v0[2]), f2bf(v0[3]) };
  us4 b = { f2bf(v1[0]), f2bf(v1[1]), f2bf(v1[2]), f2bf(v1[3]) };
  *(us4*)(xb + base)     = a;
  *(us4*)(xb + base + 4) = b;
  f32x4 z = {0.f, 0.f, 0.f, 0.f};
  *(f32x4*)(out + base)     = z;
  *(f32x4*)(out + base + 4) = z;
}

// ---- routing: counts -> 128-padded segment bases -> permutation ----
__global__ __launch_bounds__(256) void k_route(const int* __restrict__ sel,
                                               int* __restrict__ hdr,   // seg_base[9]
                                               int* __restrict__ perm) {
  __shared__ int cnt[NEXP];
  __shared__ int cur[NEXP];
  int tid = threadIdx.x;
  if (tid < NEXP) cnt[tid] = 0;
  __syncthreads();
  for (int p = tid; p < NPAIR; p += 256) atomicAdd(&cnt[sel[p]], 1);
  __syncthreads();
  if (tid == 0) {
    int acc = 0;
    for (int e = 0; e < NEXP; e++) {
      hdr[e] = acc;
      cur[e] = acc;
      acc += (cnt[e] + 127) & ~127;   // pad each segment to 128
    }
    hdr[NEXP] = acc;
  }
  __syncthreads();
  for (int i = tid; i < PERM_MAX; i += 256) perm[i] = -1;
  __syncthreads();
  for (int p = tid; p < NPAIR; p += 256) {
    int e = sel[p];
    int slot = atomicAdd(&cur[e], 1);
    perm[slot] = p;
  }
}

// ==== GEMM 1: gate + up fused, SwiGLU epilogue -> hbuf (bf16) ====
// BM=128, BN=64 (per matrix), BK=64; 4 waves in 2x2; per-wave 64x32 per matrix.
// Double-buffered LDS, prefetch next K-step before computing current.
// A: bf16 via global_load_lds (linear dest, inverse-swizzled source).
// B: f32 reg-staged, cvt_pk -> bf16, swizzled ds_write_b128.
__global__ __launch_bounds__(256) void k_gateup(const u16* __restrict__ xb,
                                                const float* __restrict__ gw,
                                                const float* __restrict__ uw,
                                                const int* __restrict__ hdr,
                                                const int* __restrict__ perm,
                                                u16* __restrict__ hbuf) {
  __shared__ __align__(16) u16 lA[2][128 * 64];   // 2 x 16 KB
  __shared__ __align__(16) u16 lBg[2][64 * 64];   // 2 x 8 KB
  __shared__ __align__(16) u16 lBu[2][64 * 64];   // 2 x 8 KB

  const int tid = threadIdx.x, lane = tid & 63, wv = tid >> 6;
  const int n0 = blockIdx.x * 64, m0 = blockIdx.y * 128;
  if (m0 >= hdr[NEXP]) return;
  int e = 0;
  #pragma unroll
  for (int k = 1; k < NEXP; k++) if (m0 >= hdr[k]) e = k;

  // A staging: 16 x 1KiB issues (4/wave). LDS linear; source inverse-swizzled.
  const u16* srcA[4]; int dstAo[4];
  #pragma unroll
  for (int j = 0; j < 4; j++) {
    int rt = wv * 32 + j * 8 + (lane >> 3);
    int p = perm[m0 + rt];
    int tok = (p < 0) ? 0 : (p >> 1);
    int sw = (lane & 7) ^ (rt & 7);
    srcA[j] = xb + (size_t)tok * HID + sw * 8;
    dstAo[j] = (wv * 32 + j * 8) * 64;
  }
  // B staging (f32): lane handles row br, 16 consecutive floats at col cb.
  const int br = wv * 16 + (lane >> 2);
  const int cb = (lane & 3) * 16;
  const size_t eb = (size_t)e * (1 << 20);
  const float* pG = gw + eb + (size_t)(n0 + br) * HID + cb;
  const float* pU = uw + eb + (size_t)(n0 + br) * HID + cb;
  const int bws0 = br * 64 + ((((lane & 3) * 2 + 0) ^ (br & 7)) * 8);
  const int bws1 = br * 64 + ((((lane & 3) * 2 + 1) ^ (br & 7)) * 8);

  const int wm = wv >> 1, wn = wv & 1;
  const int fr = lane & 15, fq = lane >> 4;

  f32x4 vg[4], vu[4];
  f32x4 accg[4][2], accu[4][2];
  #pragma unroll
  for (int a = 0; a < 4; a++)
    #pragma unroll
    for (int b = 0; b < 2; b++) {
      accg[a][b] = (f32x4){0.f, 0.f, 0.f, 0.f};
      accu[a][b] = (f32x4){0.f, 0.f, 0.f, 0.f};
    }

#define GU_ISSUE(B, K0) { const int k0_ = (K0);                                   \
    _Pragma("unroll") for (int j = 0; j < 4; j++)                                 \
      gload16(srcA[j] + k0_, &lA[B][dstAo[j]]);                                   \
    _Pragma("unroll") for (int i = 0; i < 4; i++) {                               \
      vg[i] = *(const f32x4*)(pG + k0_ + i * 4);                                  \
      vu[i] = *(const f32x4*)(pU + k0_ + i * 4);                                  \
    } }

#define GU_CVTW(B) {                                                              \
    u32x4 w0 = { pk2(vg[0][0], vg[0][1]), pk2(vg[0][2], vg[0][3]),                \
                 pk2(vg[1][0], vg[1][1]), pk2(vg[1][2], vg[1][3]) };              \
    *(u32x4*)&lBg[B][bws0] = w0;                                                  \
    u32x4 w1 = { pk2(vg[2][0], vg[2][1]), pk2(vg[2][2], vg[2][3]),                \
                 pk2(vg[3][0], vg[3][1]), pk2(vg[3][2], vg[3][3]) };              \
    *(u32x4*)&lBg[B][bws1] = w1;                                                  \
    u32x4 w2 = { pk2(vu[0][0], vu[0][1]), pk2(vu[0][2], vu[0][3]),                \
                 pk2(vu[1][0], vu[1][1]), pk2(vu[1][2], vu[1][3]) };              \
    *(u32x4*)&lBu[B][bws0] = w2;                                                  \
    u32x4 w3 = { pk2(vu[2][0], vu[2][1]), pk2(vu[2][2], vu[2][3]),                \
                 pk2(vu[3][0], vu[3][1]), pk2(vu[3][2], vu[3][3]) };              \
    *(u32x4*)&lBu[B][bws1] = w3; }

#define GU_COMP(B) {                                                              \
    _Pragma("unroll") for (int kk2 = 0; kk2 < 2; kk2++) {                         \
      bf16x8 af[4], bg[2], bu[2];                                                 \
      _Pragma("unroll") for (int m2 = 0; m2 < 4; m2++) {                          \
        int r = wm * 64 + m2 * 16 + fr, q = kk2 * 4 + fq;                         \
        af[m2] = *(const bf16x8*)&lA[B][r * 64 + (q ^ (r & 7)) * 8];              \
      }                                                                           \
      _Pragma("unroll") for (int n2 = 0; n2 < 2; n2++) {                          \
        int r = wn * 32 + n2 * 16 + fr, q = kk2 * 4 + fq;                         \
        bg[n2] = *(const bf16x8*)&lBg[B][r * 64 + (q ^ (r & 7)) * 8];             \
        bu[n2] = *(const bf16x8*)&lBu[B][r * 64 + (q ^ (r & 7)) * 8];             \
      }                                                                           \
      _Pragma("unroll") for (int m2 = 0; m2 < 4; m2++)                            \
        _Pragma("unroll") for (int n2 = 0; n2 < 2; n2++) {                        \
          accg[m2][n2] = mfma_bf16(af[m2], bg[n2], accg[m2][n2]);                 \
          accu[m2][n2] = mfma_bf16(af[m2], bu[n2], accu[m2][n2]);                 \
        }                                                                         \
    } }

  GU_ISSUE(0, 0);
  GU_CVTW(0);
  __syncthreads();
  for (int kk = 0; kk < 16; kk += 2) {
    GU_ISSUE(1, (kk + 1) * 64);
    GU_COMP(0);
    GU_CVTW(1);
    __syncthreads();
    if (kk + 2 < 16) { GU_ISSUE(0, (kk + 2) * 64); }
    GU_COMP(1);
    if (kk + 2 < 16) { GU_CVTW(0); }
    __syncthreads();
  }
#undef GU_ISSUE
#undef GU_CVTW
#undef GU_COMP

  // epilogue: h = silu(g) * u -> bf16
  #pragma unroll
  for (int m2 = 0; m2 < 4; m2++)
    #pragma unroll
    for (int n2 = 0; n2 < 2; n2++)
      #pragma unroll
      for (int q = 0; q < 4; q++) {
        int row = m0 + wm * 64 + m2 * 16 + fq * 4 + q;
        int col = n0 + wn * 32 + n2 * 16 + fr;
        float g = accg[m2][n2][q];
        float u = accu[m2][n2][q];
        float h = (g / (1.0f + __expf(-g))) * u;
        hbuf[(size_t)row * HID + col] = f2bf(h);
      }
}

// ==== GEMM 2: down, weighted atomic scatter into out ====
__global__ __launch_bounds__(256) void k_down(const u16* __restrict__ hbuf,
                                              const float* __restrict__ dw,
                                              const int* __restrict__ hdr,
                                              const int* __restrict__ perm,
                                              const float* __restrict__ rw,
                                              float* __restrict__ out) {
  __shared__ __align__(16) u16 lA[2][128 * 64];   // 2 x 16 KB
  __shared__ __align__(16) u16 lB[2][64 * 64];    // 2 x 8 KB

  const int tid = threadIdx.x, lane = tid & 63, wv = tid >> 6;
  const int n0 = blockIdx.x * 64, m0 = blockIdx.y * 128;
  if (m0 >= hdr[NEXP]) return;
  int e = 0;
  #pragma unroll
  for (int k = 1; k < NEXP; k++) if (m0 >= hdr[k]) e = k;

  const u16* srcA[4]; int dstAo[4];
  #pragma unroll
  for (int j = 0; j < 4; j++) {
    int rt = wv * 32 + j * 8 + (lane >> 3);
    int sw = (lane & 7) ^ (rt & 7);
    srcA[j] = hbuf + (size_t)(m0 + rt) * HID + sw * 8;
    dstAo[j] = (wv * 32 + j * 8) * 64;
  }
  const int br = wv * 16 + (lane >> 2);
  const int cb = (lane & 3) * 16;
  const size_t eb = (size_t)e * (1 << 20);
  const float* pB = dw + eb + (size_t)(n0 + br) * HID + cb;
  const int bws0 = br * 64 + ((((lane & 3) * 2 + 0) ^ (br & 7)) * 8);
  const int bws1 = br * 64 + ((((lane & 3) * 2 + 1) ^ (br & 7)) * 8);

  const int wm = wv >> 1, wn = wv & 1;
  const int fr = lane & 15, fq = lane >> 4;

  f32x4 vb[4];
  f32x4 acc[4][2];
  #pragma unroll
  for (int a = 0; a < 4; a++)
    #pragma unroll
    for (int b = 0; b < 2; b++) acc[a][b] = (f32x4){0.f, 0.f, 0.f, 0.f};

#define DN_ISSUE(B, K0) { const int k0_ = (K0);                                   \
    _Pragma("unroll") for (int j = 0; j < 4; j++)                                 \
      gload16(srcA[j] + k0_, &lA[B][dstAo[j]]);                                   \
    _Pragma("unroll") for (int i = 0; i < 4; i++)                                 \
      vb[i] = *(const f32x4*)(pB + k0_ + i * 4); }

#define DN_CVTW(B) {                                                              \
    u32x4 w0 = { pk2(vb[0][0], vb[0][1]), pk2(vb[0][2], vb[0][3]),                \
                 pk2(vb[1][0], vb[1][1]), pk2(vb[1][2], vb[1][3]) };              \
    *(u32x4*)&lB[B][bws0] = w0;                                                   \
    u32x4 w1 = { pk2(vb[2][0], vb[2][1]), pk2(vb[2][2], vb[2][3]),                \
                 pk2(vb[3][0], vb[3][1]), pk2(vb[3][2], vb[3][3]) };              \
    *(u32x4*)&lB[B][bws1] = w1; }

#define DN_COMP(B) {                                                              \
    _Pragma("unroll") for (int kk2 = 0; kk2 < 2; kk2++) {                         \
      bf16x8 af[4], bf[2];                                                        \
      _Pragma("unroll") for (int m2 = 0; m2 < 4; m2++) {                          \
        int r = wm * 64 + m2 * 16 + fr, q = kk2 * 4 + fq;                         \
        af[m2] = *(const bf16x8*)&lA[B][r * 64 + (q ^ (r & 7)) * 8];              \
      }                                                                           \
      _Pragma("unroll") for (int n2 = 0; n2 < 2; n2++) {                          \
        int r = wn * 32 + n2 * 16 + fr, q = kk2 * 4 + fq;                         \
        bf[n2] = *(const bf16x8*)&lB[B][r * 64 + (q ^ (r & 7)) * 8];              \
      }                                                                           \
      _Pragma("unroll") for (int m2 = 0; m2 < 4; m2++)                            \
        _Pragma("unroll") for (int n2 = 0; n2 < 2; n2++)                          \
          acc[m2][n2] = mfma_bf16(af[m2], bf[n2], acc[m2][n2]);                   \
    } }

  DN_ISSUE(0, 0);
  DN_CVTW(0);
  __syncthreads();
  for (int kk = 0; kk < 16; kk += 2) {
    DN_ISSUE(1, (kk + 1) * 64);
    DN_COMP(0);
    DN_CVTW(1);
    __syncthreads();
    if (kk + 2 < 16) { DN_ISSUE(0, (kk + 2) * 64); }
    DN_COMP(1);
    if (kk + 2 < 16) { DN_CVTW(0); }
    __syncthreads();
  }
#undef DN_ISSUE
#undef DN_CVTW
#undef DN_COMP

  // epilogue: out[token] += w * val
  #pragma unroll
  for (int m2 = 0; m2 < 4; m2++)
    #pragma unroll
    for (int q = 0; q < 4; q++) {
      int row = m0 + wm * 64 + m2 * 16 + fq * 4 + q;
      int p = perm[row];
      if (p < 0) continue;
      int t = p >> 1;
      float w = rw[p];
      #pragma unroll
      for (int n2 = 0; n2 < 2; n2++) {
        int col = n0 + wn * 32 + n2 * 16 + fr;
        atomicAdd(&out[(size_t)t * HID + col], acc[m2][n2][q] * w);
      }
    }
}

extern "C" void kernel_launch(void* const* d_in, const int* in_sizes, int n_in,
                              void* d_out, int out_size, void* d_ws, size_t ws_size,
                              hipStream_t stream) {
  const float* x   = (const float*)d_in[0];
  const float* rw  = (const float*)d_in[1];
  const int*   sel = (const int*)d_in[2];
  const float* gw  = (const float*)d_in[4];
  const float* uw  = (const float*)d_in[5];
  const float* dw  = (const float*)d_in[6];
  float* out = (float*)d_out;

  char* ws = (char*)d_ws;
  int*  hdr  = (int*)ws;                          // seg_base[9]
  int*  perm = (int*)(ws + 1024);                 // PERM_MAX ints
  u16*  xb   = (u16*)(ws + (1 << 16));            // 2M bf16 = 4 MiB
  u16*  hbuf = xb + (2 << 20);                    // 5120*1024 bf16 = 10 MiB

  k_prep <<<dim3(1024), dim3(256), 0, stream>>>(x, xb, out);
  k_route<<<dim3(1),    dim3(256), 0, stream>>>(sel, hdr, perm);
  k_gateup<<<dim3(16, MT_MAX), dim3(256), 0, stream>>>(xb, gw, uw, hdr, perm, hbuf);
  k_down  <<<dim3(16, MT_MAX), dim3(256), 0, stream>>>(hbuf, dw, hdr, perm, rw, out);
}